// Round 2
// baseline (330.706 us; speedup 1.0000x reference)
//
#include <hip/hip_runtime.h>
#include <utility>

// Problem constants: N=262144 rows, NX=NQ=64, NU=16, fp32.
#define NROWS 262144
#define BT 512                 // threads/block
#define RPB 128                // rows/block (= BT/4)

typedef float f16v __attribute__((ext_vector_type(16)));
typedef float f4v  __attribute__((ext_vector_type(4)));

// d_ws layout (floats) — two contiguous 9280-float phase blocks:
//  phase1 @0    : C1T[4096] | D11T[4096] | D12T[1024] | bv[64]
//  phase2 @9280 : AT [4096] | B1T [4096] | B2T [1024] | bx[64]
//  C1T[j*64+i]=C1[i][j]  D11T[i*64+k]=D11[k][i] (zeros at k<=i come from input)
//  D12T[j*64+i]=D12[i][j]  AT[j*64+k]=A[k][j]  B1T[i*64+k]=B1[k][i]
//  B2T[j*64+k]=B2[k][j]
// The fused kernel now stages BOTH blocks into one 74.2 KB LDS buffer.

__global__ void prep_kernel(const float* __restrict__ A, const float* __restrict__ B1,
                            const float* __restrict__ B2, const float* __restrict__ C1,
                            const float* __restrict__ D11, const float* __restrict__ D12,
                            const float* __restrict__ bv, const float* __restrict__ bx,
                            float* __restrict__ ws) {
    int g = blockIdx.x * 256 + threadIdx.x;
    if (g < 4096) {
        int r = g >> 6, c = g & 63;       // source row r, col c (64x64 row-major)
        int to = c * 64 + r;
        ws[0     + to] = C1[g];           // C1T
        ws[4096  + to] = D11[g];          // D11T
        ws[9280  + to] = A[g];            // AT
        ws[13376 + to] = B1[g];           // B1T
    }
    if (g < 1024) {
        int r = g >> 4, c = g & 15;       // 64x16 row-major source
        int to = c * 64 + r;
        ws[8192  + to] = D12[g];          // D12T
        ws[17472 + to] = B2[g];           // B2T
    }
    if (g < 64) {
        ws[9216  + g] = bv[g];
        ws[18496 + g] = bx[g];
    }
}

__device__ __forceinline__ f16v lds16(const float* p) { return *(const f16v*)p; }

// Quad-lane broadcast via DPP quad_perm:[Q,Q,Q,Q] — pure VALU (~2 cyc), no
// memory-counter interaction.
template<int Q>
__device__ __forceinline__ float qbcast(float v) {
    return __int_as_float(__builtin_amdgcn_update_dpp(
        0, __float_as_int(v), Q * 0x55, 0xF, 0xF, true));
}

// Substitution step I: broadcast w_I's pre-activation from its owner lane
// (quad lane I>>4), relu on every lane, then uniform FMA — zeros in D11T
// column I make non-future entries exact no-ops.
template<int I>
__device__ __forceinline__ void substep(f16v& s, const float* D11s, int c16, int c) {
    const float wv = fmaxf(qbcast<(I >> 4)>(s[I & 15]), 0.0f);
    s += lds16(D11s + I * 64 + c16) * wv;          // D11T[I][I]==0, safe for owner
    s[I & 15] = (c == (I >> 4)) ? wv : s[I & 15];  // owner finalizes its element
}

template<int... Is>
__device__ __forceinline__ void subst_all(f16v& s, const float* D11s, int c16, int c,
                                          std::integer_sequence<int, Is...>) {
    (substep<Is>(s, D11s, c16, c), ...);
}

// Generic LDS-matrix x register-fragment matvec: the 64 (or 16) multiplier
// scalars live distributed across the quad (16 or 4 per lane) and are
// broadcast with DPP — zero global/LDS traffic for the vector operand.
template<int J>
__device__ __forceinline__ void mv64step(f16v& a, const float* Ms, int c16, const f16v& f) {
    a += lds16(Ms + J * 64 + c16) * qbcast<(J >> 4)>(f[J & 15]);
}
template<int... Js>
__device__ __forceinline__ void mv64(f16v& a, const float* Ms, int c16, const f16v& f,
                                     std::integer_sequence<int, Js...>) {
    (mv64step<Js>(a, Ms, c16, f), ...);
}

template<int J>
__device__ __forceinline__ void mv16step(f16v& a, const float* Ms, int c16, const f4v& f) {
    a += lds16(Ms + J * 64 + c16) * qbcast<(J >> 2)>(f[J & 3]);
}
template<int... Js>
__device__ __forceinline__ void mv16(f16v& a, const float* Ms, int c16, const f4v& f,
                                     std::integer_sequence<int, Js...>) {
    (mv16step<Js>(a, Ms, c16, f), ...);
}

// Fused kernel: quad (4 lanes) per row; each lane owns a 16-output chunk.
// x/u live in quad-distributed registers (loaded ONCE, coalesced); both
// phase tables are LDS-resident simultaneously -> single barrier, no
// global loads at all inside the compute body.
__global__ __launch_bounds__(BT, 4) void renl2_fused(const float* __restrict__ x,
                                                     const float* __restrict__ u,
                                                     const float* __restrict__ ws,
                                                     float* __restrict__ out) {
    __shared__ __align__(64) float sm[18560];   // 74.24 KB -> 2 blocks/CU
    const int tid = threadIdx.x;
    const int c   = tid & 3;              // quad chunk id
    const int c16 = c << 4;
    const size_t row0 = (size_t)blockIdx.x * RPB;

    // ---- per-lane x/u fragments: lane c of row r holds x[64r+16c..+16],
    //      i.e. a fully contiguous tid*16 load. Issued first; latency hides
    //      under staging + barrier.
    const f16v xf = *(const f16v*)(x + row0 * 64 + (size_t)tid * 16);
    const f4v  uf = *(const f4v*) (u + row0 * 16 + (size_t)tid * 4);

    // ---- stage BOTH phase tables once, float4-wide ----
    const float4* wsv = (const float4*)ws;
    float4* smv = (float4*)sm;
#pragma unroll
    for (int i = 0; i < 9; i++) smv[tid + i * BT] = wsv[tid + i * BT];
    if (tid < 4640 - 9 * BT) smv[tid + 9 * BT] = wsv[tid + 9 * BT];
    __syncthreads();

    // ---- phase 1: s = bv + C1 x + D12 u ----
    f16v s = lds16(sm + 9216 + c16);
    mv64(s, sm + 0,    c16, xf, std::make_integer_sequence<int, 64>{});   // C1T
    mv16(s, sm + 8192, c16, uf, std::make_integer_sequence<int, 16>{});   // D12T

    // ---- substitution (intra-quad DPP broadcast, branchless, VALU-only) ----
    subst_all(s, sm + 4096, c16, c, std::make_integer_sequence<int, 64>{});

    // ---- phase 2 (no barrier needed: whole table already resident) ----
    // acc = bx + B1 w + A x + B2 u;  w == s (quad-register resident)
    f16v acc = lds16(sm + 18496 + c16);
    mv64(acc, sm + 13376, c16, s,  std::make_integer_sequence<int, 64>{}); // B1T·w
    mv64(acc, sm + 9280,  c16, xf, std::make_integer_sequence<int, 64>{}); // AT·x
    mv16(acc, sm + 17472, c16, uf, std::make_integer_sequence<int, 16>{}); // B2T·u

    // ---- single 64B store: x_dot ----
    *(f16v*)(out + (row0 + (size_t)(tid >> 2)) * 64 + c16) = acc;
}

extern "C" void kernel_launch(void* const* d_in, const int* in_sizes, int n_in,
                              void* d_out, int out_size, void* d_ws, size_t ws_size,
                              hipStream_t stream) {
    const float* x   = (const float*)d_in[0];
    const float* u   = (const float*)d_in[1];
    const float* A   = (const float*)d_in[2];
    const float* B1  = (const float*)d_in[3];
    const float* B2  = (const float*)d_in[4];
    const float* C1  = (const float*)d_in[5];
    const float* D11 = (const float*)d_in[6];
    const float* D12 = (const float*)d_in[7];
    const float* bv  = (const float*)d_in[8];
    const float* bx  = (const float*)d_in[9];
    float* out = (float*)d_out;
    float* ws  = (float*)d_ws;

    prep_kernel<<<16, 256, 0, stream>>>(A, B1, B2, C1, D11, D12, bv, bx, ws);
    renl2_fused<<<NROWS / RPB, BT, 0, stream>>>(x, u, ws, out);
}

// Round 3
// 282.517 us; speedup vs baseline: 1.1706x; 1.1706x over previous
//
#include <hip/hip_runtime.h>
#include <utility>

// Problem constants: N=262144 rows, NX=NQ=64, NU=16, fp32.
#define NROWS 262144
#define BT 512                 // threads/block
#define RPB 128                // rows/block (= BT/4)

typedef float f16v __attribute__((ext_vector_type(16)));
typedef float f4v  __attribute__((ext_vector_type(4)));

// d_ws layout (floats) — two contiguous 9280-float phase blocks:
//  phase1 @0    : C1T[4096] | D11T[4096] | D12T[1024] | bv[64]
//  phase2 @9280 : AT [4096] | B1T [4096] | B2T [1024] | bx[64]
//  C1T[j*64+i]=C1[i][j]  D11T[i*64+k]=D11[k][i] (zeros at k<=i come from input)
//  D12T[j*64+i]=D12[i][j]  AT[j*64+k]=A[k][j]  B1T[i*64+k]=B1[k][i]
//  B2T[j*64+k]=B2[k][j]
// The fused kernel stages BOTH blocks into one 74.2 KB LDS buffer.

__global__ void prep_kernel(const float* __restrict__ A, const float* __restrict__ B1,
                            const float* __restrict__ B2, const float* __restrict__ C1,
                            const float* __restrict__ D11, const float* __restrict__ D12,
                            const float* __restrict__ bv, const float* __restrict__ bx,
                            float* __restrict__ ws) {
    int g = blockIdx.x * 256 + threadIdx.x;
    if (g < 4096) {
        int r = g >> 6, c = g & 63;       // source row r, col c (64x64 row-major)
        int to = c * 64 + r;
        ws[0     + to] = C1[g];           // C1T
        ws[4096  + to] = D11[g];          // D11T
        ws[9280  + to] = A[g];            // AT
        ws[13376 + to] = B1[g];           // B1T
    }
    if (g < 1024) {
        int r = g >> 4, c = g & 15;       // 64x16 row-major source
        int to = c * 64 + r;
        ws[8192  + to] = D12[g];          // D12T
        ws[17472 + to] = B2[g];           // B2T
    }
    if (g < 64) {
        ws[9216  + g] = bv[g];
        ws[18496 + g] = bx[g];
    }
}

__device__ __forceinline__ f16v lds16(const float* p) { return *(const f16v*)p; }

// Quad-lane broadcast via DPP quad_perm:[Q,Q,Q,Q] — pure VALU (~2 cyc), no
// memory-counter interaction.
template<int Q>
__device__ __forceinline__ float qbcast(float v) {
    return __int_as_float(__builtin_amdgcn_update_dpp(
        0, __float_as_int(v), Q * 0x55, 0xF, 0xF, true));
}

// Substitution step I: broadcast w_I's pre-activation from its owner lane
// (quad lane I>>4), relu on every lane, then uniform FMA — zeros in D11T
// column I make non-future entries exact no-ops.
template<int I>
__device__ __forceinline__ void substep(f16v& s, const float* D11s, int c16, int c) {
    const float wv = fmaxf(qbcast<(I >> 4)>(s[I & 15]), 0.0f);
    s += lds16(D11s + I * 64 + c16) * wv;          // D11T[I][I]==0, safe for owner
    s[I & 15] = (c == (I >> 4)) ? wv : s[I & 15];  // owner finalizes its element
}

template<int... Is>
__device__ __forceinline__ void subst_all(f16v& s, const float* D11s, int c16, int c,
                                          std::integer_sequence<int, Is...>) {
    (substep<Is>(s, D11s, c16, c), ...);
}

// Generic LDS-matrix x register-fragment matvec: the 64 (or 16) multiplier
// scalars live distributed across the quad (16 or 4 per lane) and are
// broadcast with DPP — zero global/LDS traffic for the vector operand.
template<int J>
__device__ __forceinline__ void mv64step(f16v& a, const float* Ms, int c16, const f16v& f) {
    a += lds16(Ms + J * 64 + c16) * qbcast<(J >> 4)>(f[J & 15]);
}
template<int... Js>
__device__ __forceinline__ void mv64(f16v& a, const float* Ms, int c16, const f16v& f,
                                     std::integer_sequence<int, Js...>) {
    (mv64step<Js>(a, Ms, c16, f), ...);
}

template<int J>
__device__ __forceinline__ void mv16step(f16v& a, const float* Ms, int c16, const f4v& f) {
    a += lds16(Ms + J * 64 + c16) * qbcast<(J >> 2)>(f[J & 3]);
}
template<int... Js>
__device__ __forceinline__ void mv16(f16v& a, const float* Ms, int c16, const f4v& f,
                                     std::integer_sequence<int, Js...>) {
    (mv16step<Js>(a, Ms, c16, f), ...);
}

// Fused kernel: quad (4 lanes) per row; each lane owns a 16-output chunk.
// x/u live in quad-distributed registers (loaded ONCE, coalesced); both
// phase tables are LDS-resident simultaneously -> single barrier, no
// global loads at all inside the compute body.
// launch_bounds(BT, 2): 74.2 KB LDS caps at 2 blocks/CU anyway — budgeting
// for 4 (round 2) pinned VGPRs at 64 and spilled 360 MB to scratch.
__global__ __launch_bounds__(BT, 2) void renl2_fused(const float* __restrict__ x,
                                                     const float* __restrict__ u,
                                                     const float* __restrict__ ws,
                                                     float* __restrict__ out) {
    __shared__ __align__(64) float sm[18560];   // 74.24 KB -> 2 blocks/CU
    const int tid = threadIdx.x;
    const int c   = tid & 3;              // quad chunk id
    const int c16 = c << 4;
    const size_t row0 = (size_t)blockIdx.x * RPB;

    // ---- per-lane x/u fragments: lane c of row r holds x[64r+16c..+16],
    //      i.e. a fully contiguous tid*16 load. Issued first; latency hides
    //      under staging + barrier.
    const f16v xf = *(const f16v*)(x + row0 * 64 + (size_t)tid * 16);
    const f4v  uf = *(const f4v*) (u + row0 * 16 + (size_t)tid * 4);

    // ---- stage BOTH phase tables once, float4-wide ----
    const float4* wsv = (const float4*)ws;
    float4* smv = (float4*)sm;
#pragma unroll
    for (int i = 0; i < 9; i++) smv[tid + i * BT] = wsv[tid + i * BT];
    if (tid < 4640 - 9 * BT) smv[tid + 9 * BT] = wsv[tid + 9 * BT];
    __syncthreads();

    // ---- phase 1: s = bv + C1 x + D12 u ----
    f16v s = lds16(sm + 9216 + c16);
    mv64(s, sm + 0,    c16, xf, std::make_integer_sequence<int, 64>{});   // C1T
    mv16(s, sm + 8192, c16, uf, std::make_integer_sequence<int, 16>{});   // D12T

    // ---- substitution (intra-quad DPP broadcast, branchless, VALU-only) ----
    subst_all(s, sm + 4096, c16, c, std::make_integer_sequence<int, 64>{});

    // ---- phase 2 (no barrier needed: whole table already resident) ----
    // acc = bx + B1 w + A x + B2 u;  w == s (quad-register resident)
    f16v acc = lds16(sm + 18496 + c16);
    mv64(acc, sm + 13376, c16, s,  std::make_integer_sequence<int, 64>{}); // B1T·w
    mv64(acc, sm + 9280,  c16, xf, std::make_integer_sequence<int, 64>{}); // AT·x
    mv16(acc, sm + 17472, c16, uf, std::make_integer_sequence<int, 16>{}); // B2T·u

    // ---- single 64B store: x_dot ----
    *(f16v*)(out + (row0 + (size_t)(tid >> 2)) * 64 + c16) = acc;
}

extern "C" void kernel_launch(void* const* d_in, const int* in_sizes, int n_in,
                              void* d_out, int out_size, void* d_ws, size_t ws_size,
                              hipStream_t stream) {
    const float* x   = (const float*)d_in[0];
    const float* u   = (const float*)d_in[1];
    const float* A   = (const float*)d_in[2];
    const float* B1  = (const float*)d_in[3];
    const float* B2  = (const float*)d_in[4];
    const float* C1  = (const float*)d_in[5];
    const float* D11 = (const float*)d_in[6];
    const float* D12 = (const float*)d_in[7];
    const float* bv  = (const float*)d_in[8];
    const float* bx  = (const float*)d_in[9];
    float* out = (float*)d_out;
    float* ws  = (float*)d_ws;

    prep_kernel<<<16, 256, 0, stream>>>(A, B1, B2, C1, D11, D12, bv, bx, ws);
    renl2_fused<<<NROWS / RPB, BT, 0, stream>>>(x, u, ws, out);
}